// Round 2
// baseline (433.673 us; speedup 1.0000x reference)
//
#include <hip/hip_runtime.h>
#include <hip/hip_bf16.h>
#include <math.h>

#define H 1024
#define V 50257
#define L 12

// ws layout (fp32 elements)
#define OFF_EMB    0              // 1024  (contiguous with OFF_ATTN -> concat input for K2)
#define OFF_ATTN   1024           // 1024
#define OFF_X      2048           // 1024
#define OFF_H0     3072           // 1024
#define OFF_H      4096           // 1024
#define OFF_LOGITS 5120           // 50257
#define OFF_SUM    (5120 + 50260) // 1 (sum-of-exp accumulator)

// dot(v, Wrow) over K fp32 elements (K % 256 == 0), one wave.
// Lane l loads 4 contiguous floats per 256-chunk: coalesced 16B/lane.
__device__ __forceinline__ float wave_dot_f(const float* __restrict__ Wrow,
                                            const float* __restrict__ v, int K) {
    int lane = threadIdx.x & 63;
    float sum = 0.f;
    for (int c = 0; c < K; c += 256) {
        float4 w = ((const float4*)(Wrow + c))[lane];
        float4 a = ((const float4*)(v + c))[lane];
        sum += w.x * a.x + w.y * a.y + w.z * a.z + w.w * a.w;
    }
    for (int o = 32; o > 0; o >>= 1) sum += __shfl_down(sum, o);
    return sum;
}

// K1: embedding lookup, attention logits+softmax, attn_applied. 1 block.
__global__ void k1_attn(const int* tok_p, const float* hidden, const float* enc,
                        const float* emb, const float* attn_W, const float* attn_b,
                        float* ws, float* out) {
    __shared__ float att_in[2 * H];
    __shared__ float red[256];
    __shared__ float wsm[L];
    int t = threadIdx.x;
    int tok = tok_p[0];
    const float* erow = emb + (size_t)tok * H;
    for (int j = t; j < H; j += 256) {
        float e  = erow[j];
        float h0 = hidden[j];
        att_in[j]       = e;
        att_in[H + j]   = h0;
        ws[OFF_EMB + j] = e;
        ws[OFF_H0 + j]  = h0;
    }
    if (t == 0) ws[OFF_SUM] = 0.f;  // zero the exp-sum accumulator (ws is poisoned)
    __syncthreads();
    for (int l = 0; l < L; ++l) {
        float p = 0.f;
        const float* wr = attn_W + l * 2 * H;
        for (int j = t; j < 2 * H; j += 256) p += att_in[j] * wr[j];
        red[t] = p;
        __syncthreads();
        for (int s = 128; s > 0; s >>= 1) {
            if (t < s) red[t] += red[t + s];
            __syncthreads();
        }
        if (t == 0) wsm[l] = red[0] + attn_b[l];
        __syncthreads();
    }
    if (t == 0) {
        float m = wsm[0];
        for (int l = 1; l < L; ++l) m = fmaxf(m, wsm[l]);
        float s = 0.f;
        for (int l = 0; l < L; ++l) { wsm[l] = expf(wsm[l] - m); s += wsm[l]; }
        float inv = 1.f / s;
        for (int l = 0; l < L; ++l) {
            wsm[l] *= inv;
            out[V + H + l] = wsm[l];  // attn_weights output
        }
    }
    __syncthreads();
    for (int hh = t; hh < H; hh += 256) {
        float a = 0.f;
        for (int l = 0; l < L; ++l) a += wsm[l] * enc[l * H + hh];
        ws[OFF_ATTN + hh] = a;
    }
}

// K2: x = relu([emb, attn] @ comb_W.T + comb_b). 1024 rows, wave/row.
__global__ void k2_combine(const float* comb_W, const float* comb_b, float* ws) {
    int wave = threadIdx.x >> 6;
    int row = blockIdx.x * 4 + wave;
    float d = wave_dot_f(comb_W + (size_t)row * 2 * H, ws + OFF_EMB, 2 * H);
    if ((threadIdx.x & 63) == 0) {
        ws[OFF_X + row] = fmaxf(d + comb_b[row], 0.f);
    }
}

// K3: h_new = tanh(x @ Wih.T + bih + h0 @ Whh.T + bhh). 1024 rows, wave/row.
__global__ void k3_rnn(const float* Wih, const float* Whh, const float* bih,
                       const float* bhh, float* ws, float* out) {
    int wave = threadIdx.x >> 6;
    int row = blockIdx.x * 4 + wave;
    float d = wave_dot_f(Wih + (size_t)row * H, ws + OFF_X, H)
            + wave_dot_f(Whh + (size_t)row * H, ws + OFF_H0, H);
    if ((threadIdx.x & 63) == 0) {
        float h = tanhf(d + bih[row] + bhh[row]);
        ws[OFF_H + row] = h;
        out[V + row] = h;  // h_new output
    }
}

// K4: logits = h_new @ out_W.T + out_b; accumulate sum(exp(logit)).
// Grid-stride over rows; one atomicAdd per block (1024 total).
// |logit| <~ 5 so exp without max-subtraction is fp32-safe.
#define K4_BLOCKS 1024
__global__ void k4_outproj(const float* out_W, const float* out_b, float* ws) {
    __shared__ float sexp[4];
    int wave = threadIdx.x >> 6;
    int lane = threadIdx.x & 63;
    float esum = 0.f;
    for (int row = blockIdx.x * 4 + wave; row < V; row += K4_BLOCKS * 4) {
        float d = wave_dot_f(out_W + (size_t)row * H, ws + OFF_H, H) + out_b[row];
        if (lane == 0) {
            ws[OFF_LOGITS + row] = d;
            esum += expf(d);
        }
    }
    if (lane == 0) sexp[wave] = esum;
    __syncthreads();
    if (threadIdx.x == 0)
        atomicAdd(ws + OFF_SUM, sexp[0] + sexp[1] + sexp[2] + sexp[3]);
}

// K5: logp = logits - log(sum_exp).
__global__ void k5_norm(const float* ws, float* out) {
    int v = blockIdx.x * 256 + threadIdx.x;
    if (v < V) {
        float lse = logf(ws[OFF_SUM]);
        out[v] = ws[OFF_LOGITS + v] - lse;
    }
}

extern "C" void kernel_launch(void* const* d_in, const int* in_sizes, int n_in,
                              void* d_out, int out_size, void* d_ws, size_t ws_size,
                              hipStream_t stream) {
    const int*   tok    = (const int*)d_in[0];
    const float* hidden = (const float*)d_in[1];
    const float* enc    = (const float*)d_in[2];
    const float* emb    = (const float*)d_in[3];
    const float* attn_W = (const float*)d_in[4];
    const float* attn_b = (const float*)d_in[5];
    const float* comb_W = (const float*)d_in[6];
    const float* comb_b = (const float*)d_in[7];
    const float* Wih    = (const float*)d_in[8];
    const float* Whh    = (const float*)d_in[9];
    const float* bih    = (const float*)d_in[10];
    const float* bhh    = (const float*)d_in[11];
    const float* out_W  = (const float*)d_in[12];
    const float* out_b  = (const float*)d_in[13];
    float* ws  = (float*)d_ws;
    float* out = (float*)d_out;

    k1_attn   <<<1,                256, 0, stream>>>(tok, hidden, enc, emb, attn_W, attn_b, ws, out);
    k2_combine<<<H / 4,            256, 0, stream>>>(comb_W, comb_b, ws);
    k3_rnn    <<<H / 4,            256, 0, stream>>>(Wih, Whh, bih, bhh, ws, out);
    k4_outproj<<<K4_BLOCKS,        256, 0, stream>>>(out_W, out_b, ws);
    k5_norm   <<<(V + 255) / 256,  256, 0, stream>>>(ws, out);
}